// Round 10
// baseline (237.529 us; speedup 1.0000x reference)
//
#include <hip/hip_runtime.h>

#define B_ 1024
#define S_ 256
#define D_ 128
#define K_ 26
#define EST 27   // e_lds row stride (27 words: odd -> conflict-free writes/reads)

// Fused CRF kernel: one block (one wave) per batch element.
// Phase 1: emissions E[t][k] = dot(X[b][t], W[k]) straight into LDS.
// Phase 2: Viterbi recurrence (r9-proven body: publish + lgkmcnt drain + b128 gather).
// Phase 3: speculative backtrack (r9-proven) + coalesced store.
__global__ __launch_bounds__(64, 1) void crf_fused(
    const float* __restrict__ X, const float* __restrict__ W,
    const float* __restrict__ Tr, int* __restrict__ out)
{
  __shared__ float e_lds[S_ * EST];                // 27648 B
  __shared__ __align__(16) float pub[28];          // published delta vector
  __shared__ unsigned char bp[K_][260];            // 6760 B
  __shared__ unsigned char spec[K_][132];          // 3432 B
  __shared__ int path_s[S_];                       // 1024 B   (total ~38.9 KB)

  const int lane = threadIdx.x;
  const int jc   = (lane < K_) ? lane : (K_ - 1);
  const int b    = blockIdx.x;

  // ---------------- Phase 1: emissions into LDS ----------------
  {
    const float* xb = X + (size_t)b * (S_ * D_);
    for (int q = 0; q < 4; ++q) {
      const int t = q * 64 + lane;
      float acc[K_];
#pragma unroll
      for (int k = 0; k < K_; ++k) acc[k] = 0.f;
#pragma unroll
      for (int c = 0; c < 4; ++c) {
        // my row chunk: 32 floats (8x float4); lines fully consumed within window
        float4 x4[8];
        const float4* xp = reinterpret_cast<const float4*>(xb + t * D_ + c * 32);
#pragma unroll
        for (int i = 0; i < 8; ++i) x4[i] = xp[i];
        float xs[32];
#pragma unroll
        for (int i = 0; i < 8; ++i) {
          xs[4 * i + 0] = x4[i].x; xs[4 * i + 1] = x4[i].y;
          xs[4 * i + 2] = x4[i].z; xs[4 * i + 3] = x4[i].w;
        }
#pragma unroll
        for (int k = 0; k < K_; ++k) {
          const float* wr = W + k * D_ + c * 32;   // wave-uniform -> scalar loads
#pragma unroll
          for (int d = 0; d < 32; ++d) acc[k] = fmaf(xs[d], wr[d], acc[k]);
        }
      }
#pragma unroll
      for (int k = 0; k < K_; ++k) e_lds[t * EST + k] = acc[k];
    }
  }
  __syncthreads();   // cheap (single wave); orders phase-1 LDS writes vs phase-2 reads

  // full transition column for my state: tc[i] = Tr[i][jc]
  float tc[K_];
#pragma unroll
  for (int i = 0; i < K_; ++i) tc[i] = Tr[i * K_ + jc];

  // ---------------- Phase 2: recurrence (r9 body) ----------------
  float delta = e_lds[jc];                          // t = 0
  if (lane < 28) pub[lane] = -3.4e38f;
  if (lane < K_) pub[lane] = delta;
  asm volatile("s_waitcnt lgkmcnt(0)" ::: "memory");

  float4 raw[7];
  {
    const float4* p = reinterpret_cast<const float4*>(pub);
#pragma unroll
    for (int q = 0; q < 7; ++q) raw[q] = p[q];      // uniform broadcast reads
  }
  float ev_cur = e_lds[EST + jc];                   // e[1][jc], consumed at t=1

  for (int t = 1; t < S_; ++t) {
    // raw holds delta(t-1)
    float v[K_ + 2];
#pragma unroll
    for (int q = 0; q < 7; ++q) {
      v[4 * q + 0] = raw[q].x;
      v[4 * q + 1] = raw[q].y;
      v[4 * q + 2] = raw[q].z;
      v[4 * q + 3] = raw[q].w;
    }
#pragma unroll
    for (int i = 0; i < K_; ++i) v[i] += tc[i];

    // value path: max3 tree (exact)
    float m[9];
#pragma unroll
    for (int i = 0; i < 8; ++i) m[i] = fmaxf(fmaxf(v[3 * i], v[3 * i + 1]), v[3 * i + 2]);
    m[8] = fmaxf(v[24], v[25]);
    float n0 = fmaxf(fmaxf(m[0], m[1]), m[2]);
    float n1 = fmaxf(fmaxf(m[3], m[4]), m[5]);
    float n2 = fmaxf(fmaxf(m[6], m[7]), m[8]);
    float best = fmaxf(fmaxf(n0, n1), n2);

    // advance delta (same op order as reference: max + e)
    delta = best + ev_cur;

    // publish delta(t); drain; issue next gather (eq-scan below hides latency)
    if (lane < K_) pub[lane] = delta;
    asm volatile("s_waitcnt lgkmcnt(0)" ::: "memory");
    {
      const float4* p = reinterpret_cast<const float4*>(pub);
#pragma unroll
      for (int q = 0; q < 7; ++q) raw[q] = p[q];
    }

    // next-iter emission prefetch
    int tn = (t + 1 < S_) ? (t + 1) : (S_ - 1);
    ev_cur = e_lds[tn * EST + jc];

    // argmax path (fills gather latency window): first i with v[i]==best
    int c[K_];
#pragma unroll
    for (int i = 0; i < K_; ++i) c[i] = (v[i] == best) ? i : 63;
    int q9[9];
#pragma unroll
    for (int i = 0; i < 8; ++i) {
      int a = c[3 * i] < c[3 * i + 1] ? c[3 * i] : c[3 * i + 1];
      q9[i] = a < c[3 * i + 2] ? a : c[3 * i + 2];
    }
    q9[8] = c[24] < c[25] ? c[24] : c[25];
    int r0 = q9[0] < q9[1] ? q9[0] : q9[1]; r0 = r0 < q9[2] ? r0 : q9[2];
    int r1 = q9[3] < q9[4] ? q9[3] : q9[4]; r1 = r1 < q9[5] ? r1 : q9[5];
    int r2 = q9[6] < q9[7] ? q9[6] : q9[7]; r2 = r2 < q9[8] ? r2 : q9[8];
    int idx = r0 < r1 ? r0 : r1; idx = idx < r2 ? idx : r2;

    if (lane < K_) bp[lane][t] = (unsigned char)idx;
  }

  // final first-argmax over delta(255) (raw holds it, uniform on all lanes)
  int last;
  {
    float v[K_];
#pragma unroll
    for (int q = 0; q < 7; ++q) {
      if (4 * q + 0 < K_) v[4 * q + 0] = raw[q].x;
      if (4 * q + 1 < K_) v[4 * q + 1] = raw[q].y;
      if (4 * q + 2 < K_) v[4 * q + 2] = raw[q].z;
      if (4 * q + 3 < K_) v[4 * q + 3] = raw[q].w;
    }
    float bf = v[0];
#pragma unroll
    for (int i = 1; i < K_; ++i) bf = fmaxf(bf, v[i]);
    int iA = 63;
#pragma unroll
    for (int i = K_ - 1; i >= 0; --i) iA = (v[i] == bf) ? i : iA;
    last = iA;
  }

  __syncthreads();

  // ---------------- Phase 3: backtrack (r9-proven) ----------------
  // real chain (lane 63) t=255..129 concurrent with 26 speculative chains
  // (lanes 0..25) covering t=128..1 for every possible state@128.
  {
    int c = (lane < K_) ? lane : last;
    for (int k = 0; k < 128; ++k) {
      int t = (lane < K_) ? (128 - k) : (255 - k);
      bool act = (lane < K_) || (lane == 63 && k <= 126);
      if (act) {
        c = bp[c][t];
        if (lane < K_) spec[lane][t - 1] = (unsigned char)c;
        else if (t >= 129) path_s[t - 1] = c;   // covers 128..254
      }
    }
  }
  __syncthreads();

  {
    int sstar = path_s[128];
#pragma unroll
    for (int q2 = 0; q2 < 2; ++q2) {
      int t = q2 * 64 + lane;
      path_s[t] = (int)spec[sstar][t];
    }
    if (lane == 0) path_s[S_ - 1] = last;
  }
  __syncthreads();

  int* o = out + (size_t)b * S_;
#pragma unroll
  for (int q2 = 0; q2 < 4; ++q2) o[q2 * 64 + lane] = path_s[q2 * 64 + lane];
}

extern "C" void kernel_launch(void* const* d_in, const int* in_sizes, int n_in,
                              void* d_out, int out_size, void* d_ws, size_t ws_size,
                              hipStream_t stream) {
  (void)in_sizes; (void)n_in; (void)out_size; (void)d_ws; (void)ws_size;
  const float* X  = (const float*)d_in[0];
  const float* W  = (const float*)d_in[1];
  const float* Tr = (const float*)d_in[2];
  int* outp = (int*)d_out;
  crf_fused<<<B_, 64, 0, stream>>>(X, W, Tr, outp);
}

// Round 11
// 171.628 us; speedup vs baseline: 1.3840x; 1.3840x over previous
//
#include <hip/hip_runtime.h>

#define B_ 1024
#define S_ 256
#define D_ 128
#define K_ 26

// ---------------- Kernel 1: emissions E[b][t][k] = dot(X[b][t], W[k]) ----------------
__global__ __launch_bounds__(256, 2) void emis_kernel(
    const float* __restrict__ X, const float* __restrict__ W, float* __restrict__ E)
{
  __shared__ float xt[64][132];
  const int tid = threadIdx.x;
  const int b   = blockIdx.x >> 2;
  const int r0  = (blockIdx.x & 3) << 6;

  {
    const float4* Xs = reinterpret_cast<const float4*>(X + ((size_t)b * S_ + r0) * D_);
#pragma unroll
    for (int it = 0; it < 8; ++it) {
      int i = it * 256 + tid;
      float4 v = Xs[i];
      int row = i >> 5, col = (i & 31) << 2;
      *reinterpret_cast<float4*>(&xt[row][col]) = v;
    }
  }
  __syncthreads();

  const int l = tid & 63;
  const int g = __builtin_amdgcn_readfirstlane(tid >> 6);
  const int k0 = (g < 2) ? 7 * g : 6 * g + 2;
  const int kn = (g < 2) ? 7 : 6;

  float acc[7][4];
#pragma unroll
  for (int kk = 0; kk < 7; ++kk)
#pragma unroll
    for (int c = 0; c < 4; ++c) acc[kk][c] = 0.f;

#pragma unroll
  for (int dc = 0; dc < 16; ++dc) {
    float4 a0 = *reinterpret_cast<const float4*>(&xt[l][dc * 8]);
    float4 a1 = *reinterpret_cast<const float4*>(&xt[l][dc * 8 + 4]);
    float xv[8] = {a0.x, a0.y, a0.z, a0.w, a1.x, a1.y, a1.z, a1.w};
#pragma unroll
    for (int kk = 0; kk < 7; ++kk) {
      int k = k0 + kk; k = (k > K_ - 1) ? (K_ - 1) : k;
      const float* wr = W + k * D_ + dc * 8;
#pragma unroll
      for (int dd = 0; dd < 8; ++dd)
        acc[kk][dd & 3] = fmaf(xv[dd], wr[dd], acc[kk][dd & 3]);
    }
  }

  float* eb = E + ((size_t)b * S_ + r0 + l) * K_ + k0;
#pragma unroll
  for (int kk = 0; kk < 7; ++kk)
    if (kk < kn)
      eb[kk] = (acc[kk][0] + acc[kk][1]) + (acc[kk][2] + acc[kk][3]);
}

// -------- Kernel 2: Viterbi. r9 structure; HW drain removed (same-wave LDS pipe is
// in-order; compiler fence alone prevents hoisting the gather above the publish).
__global__ __launch_bounds__(64, 1) void viterbi_kernel(
    const float* __restrict__ E, const float* __restrict__ Tr, int* __restrict__ out)
{
  __shared__ __align__(16) float e_lds[S_ * K_];   // 26624 B
  __shared__ __align__(16) float pub[28];          // published delta vector
  __shared__ unsigned char bp[K_][260];
  __shared__ unsigned char spec[K_][132];
  __shared__ int path_s[S_];

  const int lane = threadIdx.x;
  const int jc   = (lane < K_) ? lane : (K_ - 1);
  const int b    = blockIdx.x;

  float tc[K_];
#pragma unroll
  for (int i = 0; i < K_; ++i) tc[i] = Tr[i * K_ + jc];

  // ---- stage E[b] to LDS (26 float4/lane, batched in two halves)
  {
    const float4* src = reinterpret_cast<const float4*>(E + (size_t)b * (S_ * K_));
    float4* dst = reinterpret_cast<float4*>(e_lds);
#pragma unroll
    for (int half = 0; half < 2; ++half) {
      float4 tmp[13];
#pragma unroll
      for (int i = 0; i < 13; ++i) tmp[i] = src[(half * 13 + i) * 64 + lane];
#pragma unroll
      for (int i = 0; i < 13; ++i) dst[(half * 13 + i) * 64 + lane] = tmp[i];
    }
  }
  __syncthreads();                                  // staging visible before reads

  // t = 0 publish + first gather (compiler fence keeps write->read program order;
  // LDS pipe processes same-wave DS ops in order)
  float delta = e_lds[jc];
  if (lane < 28) pub[lane] = -3.4e38f;
  if (lane < K_) pub[lane] = delta;
  asm volatile("" ::: "memory");

  float4 raw[7];
  {
    const float4* p = reinterpret_cast<const float4*>(pub);
#pragma unroll
    for (int q = 0; q < 7; ++q) raw[q] = p[q];      // uniform broadcast reads
  }
  float ev_cur = e_lds[K_ + jc];                    // e[1][jc], consumed at t=1

  for (int t = 1; t < S_; ++t) {
    // raw holds delta(t-1)
    float v[K_ + 2];
#pragma unroll
    for (int q = 0; q < 7; ++q) {
      v[4 * q + 0] = raw[q].x;
      v[4 * q + 1] = raw[q].y;
      v[4 * q + 2] = raw[q].z;
      v[4 * q + 3] = raw[q].w;
    }
#pragma unroll
    for (int i = 0; i < K_; ++i) v[i] += tc[i];

    // value path: max3 tree (exact)
    float m[9];
#pragma unroll
    for (int i = 0; i < 8; ++i) m[i] = fmaxf(fmaxf(v[3 * i], v[3 * i + 1]), v[3 * i + 2]);
    m[8] = fmaxf(v[24], v[25]);
    float n0 = fmaxf(fmaxf(m[0], m[1]), m[2]);
    float n1 = fmaxf(fmaxf(m[3], m[4]), m[5]);
    float n2 = fmaxf(fmaxf(m[6], m[7]), m[8]);
    float best = fmaxf(fmaxf(n0, n1), n2);

    // advance delta (same op order as reference: max + e)
    delta = best + ev_cur;

    // publish delta(t); compiler fence; issue next gather (same-wave DS in-order,
    // compiler auto-waits before raw[] is consumed next iteration)
    if (lane < K_) pub[lane] = delta;
    asm volatile("" ::: "memory");
    {
      const float4* p = reinterpret_cast<const float4*>(pub);
#pragma unroll
      for (int q = 0; q < 7; ++q) raw[q] = p[q];
    }

    // next-iter emission prefetch (issued after gather; consumed next iter)
    int tn = (t + 1 < S_) ? (t + 1) : (S_ - 1);
    ev_cur = e_lds[tn * K_ + jc];

    // argmax path (fills the gather latency window): first i with v[i]==best
    int c[K_];
#pragma unroll
    for (int i = 0; i < K_; ++i) c[i] = (v[i] == best) ? i : 63;
    int q9[9];
#pragma unroll
    for (int i = 0; i < 8; ++i) {
      int a = c[3 * i] < c[3 * i + 1] ? c[3 * i] : c[3 * i + 1];
      q9[i] = a < c[3 * i + 2] ? a : c[3 * i + 2];
    }
    q9[8] = c[24] < c[25] ? c[24] : c[25];
    int r0 = q9[0] < q9[1] ? q9[0] : q9[1]; r0 = r0 < q9[2] ? r0 : q9[2];
    int r1 = q9[3] < q9[4] ? q9[3] : q9[4]; r1 = r1 < q9[5] ? r1 : q9[5];
    int r2 = q9[6] < q9[7] ? q9[6] : q9[7]; r2 = r2 < q9[8] ? r2 : q9[8];
    int idx = r0 < r1 ? r0 : r1; idx = idx < r2 ? idx : r2;

    if (lane < K_) bp[lane][t] = (unsigned char)idx;
  }

  // final first-argmax over delta(255) (raw holds it, uniform on all lanes)
  int last;
  {
    float v[K_];
#pragma unroll
    for (int q = 0; q < 7; ++q) {
      if (4 * q + 0 < K_) v[4 * q + 0] = raw[q].x;
      if (4 * q + 1 < K_) v[4 * q + 1] = raw[q].y;
      if (4 * q + 2 < K_) v[4 * q + 2] = raw[q].z;
      if (4 * q + 3 < K_) v[4 * q + 3] = raw[q].w;
    }
    float bf = v[0];
#pragma unroll
    for (int i = 1; i < K_; ++i) bf = fmaxf(bf, v[i]);
    int iA = 63;
#pragma unroll
    for (int i = K_ - 1; i >= 0; --i) iA = (v[i] == bf) ? i : iA;
    last = iA;
  }

  __syncthreads();

  // backtrack: real chain (lane 63) t=255..129 concurrent with 26 speculative
  // chains (lanes 0..25) covering t=128..1 for every possible state@128.
  {
    int c = (lane < K_) ? lane : last;
    for (int k = 0; k < 128; ++k) {
      int t = (lane < K_) ? (128 - k) : (255 - k);
      bool act = (lane < K_) || (lane == 63 && k <= 126);
      if (act) {
        c = bp[c][t];
        if (lane < K_) spec[lane][t - 1] = (unsigned char)c;
        else if (t >= 129) path_s[t - 1] = c;   // covers 128..254
      }
    }
  }
  __syncthreads();

  {
    int sstar = path_s[128];
#pragma unroll
    for (int q2 = 0; q2 < 2; ++q2) {
      int t = q2 * 64 + lane;
      path_s[t] = (int)spec[sstar][t];
    }
    if (lane == 0) path_s[S_ - 1] = last;
  }
  __syncthreads();

  int* o = out + (size_t)b * S_;
#pragma unroll
  for (int q2 = 0; q2 < 4; ++q2) o[q2 * 64 + lane] = path_s[q2 * 64 + lane];
}

extern "C" void kernel_launch(void* const* d_in, const int* in_sizes, int n_in,
                              void* d_out, int out_size, void* d_ws, size_t ws_size,
                              hipStream_t stream) {
  (void)in_sizes; (void)n_in; (void)out_size; (void)ws_size;
  const float* X  = (const float*)d_in[0];
  const float* W  = (const float*)d_in[1];
  const float* Tr = (const float*)d_in[2];
  float* E = (float*)d_ws;             // needs B*S*K*4 = 27,262,976 B of scratch
  int* outp = (int*)d_out;

  emis_kernel<<<B_ * 4, 256, 0, stream>>>(X, W, E);
  viterbi_kernel<<<B_, 64, 0, stream>>>(E, Tr, outp);
}